// Round 17
// baseline (127.812 us; speedup 1.0000x reference)
//
#include <hip/hip_runtime.h>

#define NUM_USERS 60000
#define NUM_ITEMS 40000
#define NUM_NODES 100000
#define DIM       64
#define NUM_EDGES 1200000
#define BATCH     16384

#define BROWS 256                 // rows per bucket
#define NBUCK 391                 // ceil(100000/256)
#define CAP   4096                // padded slots per bucket (mean 3072, +18 sigma)
#define EPB   8192                // edges per bin block -> 147 bin blocks
#define PREPBLK 512               // prep kernel block size
#define NB_BIN 147                // ceil(NUM_EDGES / EPB)
#define NB_CONV 1024              // convert blocks inside prep
#define FSLICE 223                // ceil(2*BATCH / NB_BIN) flag indices per block
#define ZWORDS (512 + 256 + 3200) // gcursor + nrows + flags (contiguous)

// ---------------------------------------------------------------------------
// bf16 helpers
// ---------------------------------------------------------------------------
__device__ __forceinline__ unsigned short f2bf(float f) {
    unsigned u = __float_as_uint(f);
    unsigned r = (u + 0x7FFFu + ((u >> 16) & 1u)) >> 16;   // RNE
    return (unsigned short)r;
}
__device__ __forceinline__ unsigned pack2bf(float a, float b) {
    return (unsigned)f2bf(a) | ((unsigned)f2bf(b) << 16);
}

// ---------------------------------------------------------------------------
// 1) fused prep: blocks [0,NB_BIN) bin edges into 391 row-buckets (+ batch
//    flagging); blocks [NB_BIN, NB_BIN+NB_CONV) convert embeddings to bf16.
//    Packed edge u64: [val:32][lrow:8][col:17]
// ---------------------------------------------------------------------------
__global__ __launch_bounds__(PREPBLK) void prep_kernel(
    const int* __restrict__ rows, const int* __restrict__ cols,
    const float* __restrict__ vals,
    const int* __restrict__ uidx, const int* __restrict__ iidx,
    const float4* __restrict__ ue, const float4* __restrict__ ie,
    ushort4* __restrict__ xc,
    int* __restrict__ gcursor, unsigned* __restrict__ flags,
    unsigned long long* __restrict__ tmp)
{
    __shared__ int cnt[NBUCK], lcur[NBUCK], gbase[NBUCK];
    int t = threadIdx.x;
    if (blockIdx.x >= NB_BIN) {
        // ---- convert branch ----
        const int nU4 = NUM_USERS * (DIM / 4);       // 960000
        const int total4 = NUM_NODES * (DIM / 4);    // 1600000
        int i = (blockIdx.x - NB_BIN) * PREPBLK + t;
        int stride = NB_CONV * PREPBLK;
        for (; i < total4; i += stride) {
            float4 v = (i < nU4) ? ue[i] : ie[i - nU4];
            ushort4 s;
            s.x = f2bf(v.x); s.y = f2bf(v.y); s.z = f2bf(v.z); s.w = f2bf(v.w);
            xc[i] = s;
        }
        return;
    }
    // ---- bin branch ----
    for (int i = t; i < NBUCK; i += PREPBLK) { cnt[i] = 0; lcur[i] = 0; }
    int fbase = blockIdx.x * FSLICE;
    for (int k = t; k < FSLICE; k += PREPBLK) {
        int gi = fbase + k;
        if (gi < BATCH) {
            int n = uidx[gi];
            atomicOr(&flags[n >> 5], 1u << (n & 31));
        } else if (gi < 2 * BATCH) {
            int n = NUM_USERS + iidx[gi - BATCH];
            atomicOr(&flags[n >> 5], 1u << (n & 31));
        }
    }
    __syncthreads();
    int base = blockIdx.x * EPB;
    int lim = NUM_EDGES - base; if (lim > EPB) lim = EPB;
    for (int k = t; k < lim; k += PREPBLK)
        atomicAdd(&cnt[rows[base + k] >> 8], 1);
    __syncthreads();
    for (int i = t; i < NBUCK; i += PREPBLK) {
        int c = cnt[i];
        gbase[i] = c ? atomicAdd(&gcursor[i], c) : 0;
    }
    __syncthreads();
    for (int k = t; k < lim; k += PREPBLK) {
        int idx = base + k;
        int r = rows[idx];
        int b = r >> 8;
        int lofs = atomicAdd(&lcur[b], 1);
        unsigned long long packed =
            ((unsigned long long)(unsigned)__float_as_int(vals[idx]) << 32)
            | ((unsigned)(r & 255) << 17) | (unsigned)cols[idx];
        tmp[(size_t)b * CAP + gbase[b] + lofs] = packed;
    }
}

// ---------------------------------------------------------------------------
// 2) per-bucket counting sort by lrow -> rse + padded CSR at b*CAP.
//    Direct scatter to csr: the 32 KB window is L2-resident, so random 8-B
//    stores line-merge in cache (no LDS stage -> 3 KB LDS, high occupancy).
//    Fused: emit needed-rows list for layer 3 (flags -> rowlist/nrows).
// ---------------------------------------------------------------------------
__global__ __launch_bounds__(256) void sort_buckets(
    const unsigned long long* __restrict__ tmp, const int* __restrict__ gcursor,
    const unsigned* __restrict__ flags, int* __restrict__ rowlist,
    int* __restrict__ nrows,
    int2* __restrict__ rse, int2* __restrict__ csr)
{
    __shared__ int lcnt[BROWS], rowcur[BROWS], sdata[BROWS];   // 3 KB
    int b = blockIdx.x;
    int t = threadIdx.x;
    int count = gcursor[b];
    int base  = b * CAP;
    const unsigned long long* src = tmp + (size_t)base;
    lcnt[t] = 0;
    __syncthreads();
    for (int i = t; i < count; i += 256)
        atomicAdd(&lcnt[(int)((src[i] >> 17) & 255)], 1);
    __syncthreads();
    int myc = lcnt[t];
    sdata[t] = myc;
    __syncthreads();
    #pragma unroll
    for (int off = 1; off < 256; off <<= 1) {
        int x = (t >= off) ? sdata[t - off] : 0;
        __syncthreads();
        sdata[t] += x;
        __syncthreads();
    }
    int excl = sdata[t] - myc;
    rowcur[t] = excl;
    int row = b * BROWS + t;
    if (row < NUM_NODES) {
        rse[row] = make_int2(base + excl, base + excl + myc);
        // fused compact_rows
        if ((flags[row >> 5] >> (row & 31)) & 1u) {
            int pos = atomicAdd(nrows, 1);
            rowlist[pos] = row;
        }
    }
    __syncthreads();
    for (int i = t; i < count; i += 256) {
        unsigned long long v = src[i];
        int lr = (int)((v >> 17) & 255);
        int pos = atomicAdd(&rowcur[lr], 1);
        csr[(size_t)base + pos] = make_int2((int)(v & 0x1FFFF), (int)(v >> 32));
    }
}

// ---------------------------------------------------------------------------
// bf16 gather + row accumulate: 8 lanes/row, 16 B (8 bf16) per lane,
// 4x unroll -> 32 independent 128B gathers in flight per wave.
// ---------------------------------------------------------------------------
__device__ __forceinline__ void fma8(
    float acc[8], unsigned long long hx, unsigned long long hy, float v)
{
    unsigned h0 = (unsigned)hx, h1 = (unsigned)(hx >> 32);
    unsigned h2 = (unsigned)hy, h3 = (unsigned)(hy >> 32);
    acc[0] = fmaf(v, __uint_as_float(h0 << 16), acc[0]);
    acc[1] = fmaf(v, __uint_as_float(h0 & 0xFFFF0000u), acc[1]);
    acc[2] = fmaf(v, __uint_as_float(h1 << 16), acc[2]);
    acc[3] = fmaf(v, __uint_as_float(h1 & 0xFFFF0000u), acc[3]);
    acc[4] = fmaf(v, __uint_as_float(h2 << 16), acc[4]);
    acc[5] = fmaf(v, __uint_as_float(h2 & 0xFFFF0000u), acc[5]);
    acc[6] = fmaf(v, __uint_as_float(h3 << 16), acc[6]);
    acc[7] = fmaf(v, __uint_as_float(h3 & 0xFFFF0000u), acc[7]);
}

__device__ __forceinline__ void row_accum8(
    int e, int end, int q, const int2* __restrict__ csr,
    const unsigned short* __restrict__ x16, float acc[8])
{
    typedef unsigned long long u64;
    for (; e + 3 < end; e += 4) {
        int2 p0 = csr[e], p1 = csr[e + 1], p2 = csr[e + 2], p3 = csr[e + 3];
        const u64* s0 = (const u64*)(x16 + ((size_t)p0.x << 6) + (q << 3));
        const u64* s1 = (const u64*)(x16 + ((size_t)p1.x << 6) + (q << 3));
        const u64* s2 = (const u64*)(x16 + ((size_t)p2.x << 6) + (q << 3));
        const u64* s3 = (const u64*)(x16 + ((size_t)p3.x << 6) + (q << 3));
        u64 a0 = s0[0], b0 = s0[1];
        u64 a1 = s1[0], b1 = s1[1];
        u64 a2 = s2[0], b2 = s2[1];
        u64 a3 = s3[0], b3 = s3[1];
        fma8(acc, a0, b0, __int_as_float(p0.y));
        fma8(acc, a1, b1, __int_as_float(p1.y));
        fma8(acc, a2, b2, __int_as_float(p2.y));
        fma8(acc, a3, b3, __int_as_float(p3.y));
    }
    for (; e < end; ++e) {
        int2 p0 = csr[e];
        const u64* s0 = (const u64*)(x16 + ((size_t)p0.x << 6) + (q << 3));
        u64 a0 = s0[0], b0 = s0[1];
        fma8(acc, a0, b0, __int_as_float(p0.y));
    }
}

// dense layer: bf16 in, bf16 out (layers 1 and 2); 8 lanes/row
__global__ __launch_bounds__(256) void spmm_bb(
    const int2* __restrict__ rse, const int2* __restrict__ csr,
    const unsigned short* __restrict__ x16, unsigned short* __restrict__ y16)
{
    int tid = blockIdx.x * blockDim.x + threadIdx.x;
    int row = tid >> 3;
    if (row >= NUM_NODES) return;
    int q = tid & 7;
    int2 se = rse[row];
    float acc[8] = {0.f, 0.f, 0.f, 0.f, 0.f, 0.f, 0.f, 0.f};
    row_accum8(se.x, se.y, q, csr, x16, acc);
    uint4 s;
    s.x = pack2bf(acc[0], acc[1]);
    s.y = pack2bf(acc[2], acc[3]);
    s.z = pack2bf(acc[4], acc[5]);
    s.w = pack2bf(acc[6], acc[7]);
    *(uint4*)(y16 + ((size_t)row << 6) + (q << 3)) = s;
}

// layer 3: listed rows only, bf16 in, fp32 out; 8 lanes/row
__global__ __launch_bounds__(256) void spmm_l3(
    const int* __restrict__ list, const int* __restrict__ nrowsp,
    const int2* __restrict__ rse, const int2* __restrict__ csr,
    const unsigned short* __restrict__ x16, float* __restrict__ y)
{
    int tid = blockIdx.x * blockDim.x + threadIdx.x;
    int i = tid >> 3;
    if (i >= *nrowsp) return;
    int q = tid & 7;
    int row = list[i];
    int2 se = rse[row];
    float acc[8] = {0.f, 0.f, 0.f, 0.f, 0.f, 0.f, 0.f, 0.f};
    row_accum8(se.x, se.y, q, csr, x16, acc);
    float4* yb = (float4*)(y + ((size_t)row << 6) + (q << 3));
    yb[0] = make_float4(acc[0], acc[1], acc[2], acc[3]);
    yb[1] = make_float4(acc[4], acc[5], acc[6], acc[7]);
}

// ---------------------------------------------------------------------------
// batched dot: one wave per batch element
// ---------------------------------------------------------------------------
__global__ __launch_bounds__(256) void dot_kernel(
    const int*   __restrict__ uidx,
    const int*   __restrict__ iidx,
    const float* __restrict__ x,
    float*       __restrict__ out)
{
    int wid  = (blockIdx.x * blockDim.x + threadIdx.x) >> 6;
    int lane = threadIdx.x & 63;
    if (wid >= BATCH) return;
    int u  = uidx[wid];
    int it = iidx[wid];
    float a = x[(size_t)u * DIM + lane];
    float bb = x[((size_t)NUM_USERS + it) * DIM + lane];
    float p = a * bb;
    #pragma unroll
    for (int off = 32; off > 0; off >>= 1)
        p += __shfl_down(p, off);
    if (lane == 0) out[wid] = p;
}

extern "C" void kernel_launch(void* const* d_in, const int* in_sizes, int n_in,
                              void* d_out, int out_size, void* d_ws, size_t ws_size,
                              hipStream_t stream)
{
    const int*   user_indices = (const int*)  d_in[0];
    const int*   item_indices = (const int*)  d_in[1];
    const int*   edge_rows    = (const int*)  d_in[2];
    const int*   edge_cols    = (const int*)  d_in[3];
    const float* edge_vals    = (const float*)d_in[4];
    const float* user_emb     = (const float*)d_in[5];
    const float* item_emb     = (const float*)d_in[6];
    float*       out          = (float*)      d_out;

    // ---- workspace layout ----
    // Alias: bufA (l3 fp32 out, 25.6 MB) overlays tmp (dead after sort_buckets)
    // + xc (dead after layer 1). l3 reads b16A (disjoint region).
    const size_t nfloats = (size_t)NUM_NODES * DIM;   // 6.4M elements
    char* p = (char*)d_ws;
    float* bufA = (float*)p;                            // 25.6 MB span (alias)
    unsigned long long* tmp = (unsigned long long*)p;
    p += (size_t)NBUCK * CAP * 8;                       // 12.81 MB
    unsigned short* xc   = (unsigned short*)p;  p += nfloats * 2;   // 12.8 MB
    unsigned short* b16B = (unsigned short*)p;  p += nfloats * 2;   // 12.8 MB
    unsigned short* b16A = (unsigned short*)p;  p += nfloats * 2;   // 12.8 MB
    int2*     rse     = (int2*)p;     p += 102400 * 8;
    // next three regions contiguous; zeroed by the memset (ZWORDS words)
    int*      gcursor = (int*)p;      p += 512 * 4;
    int*      nrows   = (int*)p;      p += 256 * 4;
    unsigned* flags   = (unsigned*)p; p += 3200 * 4;
    int*      rowlist = (int*)p;      p += 33024 * 4;
    int2*     csr     = (int2*)p;     p += (size_t)NBUCK * CAP * 8; // 12.81 MB

    // ---- zero counters (15.9 KB), fused prep (bin || convert), sort ----
    hipMemsetAsync(gcursor, 0, ZWORDS * sizeof(int), stream);
    prep_kernel<<<NB_BIN + NB_CONV, PREPBLK, 0, stream>>>(
        edge_rows, edge_cols, edge_vals, user_indices, item_indices,
        (const float4*)user_emb, (const float4*)item_emb, (ushort4*)xc,
        gcursor, flags, tmp);
    sort_buckets<<<NBUCK, 256, 0, stream>>>(
        tmp, gcursor, flags, rowlist, nrows, rse, csr);

    // ---- 3 SpMM layers: bf16->bf16, bf16->bf16, bf16->fp32(listed) ----
    const int NB_SPMM = (NUM_NODES * 8 + 255) / 256;   // 3125
    spmm_bb<<<NB_SPMM, 256, 0, stream>>>(rse, csr, xc, b16B);
    spmm_bb<<<NB_SPMM, 256, 0, stream>>>(rse, csr, b16B, b16A);
    spmm_l3<<<(32768 * 8) / 256, 256, 0, stream>>>(
        rowlist, nrows, rse, csr, b16A, bufA);

    // ---- final dot ----
    dot_kernel<<<(BATCH * 64) / 256, 256, 0, stream>>>(
        user_indices, item_indices, bufA, out);
}

// Round 18
// 127.652 us; speedup vs baseline: 1.0013x; 1.0013x over previous
//
#include <hip/hip_runtime.h>

#define NUM_USERS 60000
#define NUM_ITEMS 40000
#define NUM_NODES 100000
#define DIM       64
#define NUM_EDGES 1200000
#define BATCH     16384

#define BROWS 256                 // rows per bucket
#define NBUCK 391                 // ceil(100000/256)
#define CAP   4096                // padded slots per bucket (mean 3072, +18 sigma)
#define EPB   4096                // edges per bin block -> 293 bin blocks
#define PREPBLK 512               // prep kernel block size
#define NB_BIN 293                // ceil(NUM_EDGES / EPB)
#define NB_CONV 1024              // convert blocks inside prep
#define FSLICE 112                // ceil(2*BATCH / NB_BIN) flag indices per block
#define ZWORDS (512 + 256 + 3200) // gcursor + nrows + flags (contiguous)

// ---------------------------------------------------------------------------
// bf16 helpers
// ---------------------------------------------------------------------------
__device__ __forceinline__ unsigned short f2bf(float f) {
    unsigned u = __float_as_uint(f);
    unsigned r = (u + 0x7FFFu + ((u >> 16) & 1u)) >> 16;   // RNE
    return (unsigned short)r;
}
__device__ __forceinline__ unsigned pack2bf(float a, float b) {
    return (unsigned)f2bf(a) | ((unsigned)f2bf(b) << 16);
}

// ---------------------------------------------------------------------------
// 1) fused prep: blocks [0,NB_BIN) bin edges into 391 row-buckets (+ batch
//    flagging); blocks [NB_BIN, NB_BIN+NB_CONV) convert embeddings to bf16.
//    Packed edge u64: [val:32][lrow:8][col:17]
// ---------------------------------------------------------------------------
__global__ __launch_bounds__(PREPBLK) void prep_kernel(
    const int* __restrict__ rows, const int* __restrict__ cols,
    const float* __restrict__ vals,
    const int* __restrict__ uidx, const int* __restrict__ iidx,
    const float4* __restrict__ ue, const float4* __restrict__ ie,
    ushort4* __restrict__ xc,
    int* __restrict__ gcursor, unsigned* __restrict__ flags,
    unsigned long long* __restrict__ tmp)
{
    __shared__ int cnt[NBUCK], lcur[NBUCK], gbase[NBUCK];
    int t = threadIdx.x;
    if (blockIdx.x >= NB_BIN) {
        // ---- convert branch ----
        const int nU4 = NUM_USERS * (DIM / 4);       // 960000
        const int total4 = NUM_NODES * (DIM / 4);    // 1600000
        int i = (blockIdx.x - NB_BIN) * PREPBLK + t;
        int stride = NB_CONV * PREPBLK;
        for (; i < total4; i += stride) {
            float4 v = (i < nU4) ? ue[i] : ie[i - nU4];
            ushort4 s;
            s.x = f2bf(v.x); s.y = f2bf(v.y); s.z = f2bf(v.z); s.w = f2bf(v.w);
            xc[i] = s;
        }
        return;
    }
    // ---- bin branch ----
    for (int i = t; i < NBUCK; i += PREPBLK) { cnt[i] = 0; lcur[i] = 0; }
    int fbase = blockIdx.x * FSLICE;
    for (int k = t; k < FSLICE; k += PREPBLK) {
        int gi = fbase + k;
        if (gi < BATCH) {
            int n = uidx[gi];
            atomicOr(&flags[n >> 5], 1u << (n & 31));
        } else if (gi < 2 * BATCH) {
            int n = NUM_USERS + iidx[gi - BATCH];
            atomicOr(&flags[n >> 5], 1u << (n & 31));
        }
    }
    __syncthreads();
    int base = blockIdx.x * EPB;
    int lim = NUM_EDGES - base; if (lim > EPB) lim = EPB;
    for (int k = t; k < lim; k += PREPBLK)
        atomicAdd(&cnt[rows[base + k] >> 8], 1);
    __syncthreads();
    for (int i = t; i < NBUCK; i += PREPBLK) {
        int c = cnt[i];
        gbase[i] = c ? atomicAdd(&gcursor[i], c) : 0;
    }
    __syncthreads();
    for (int k = t; k < lim; k += PREPBLK) {
        int idx = base + k;
        int r = rows[idx];
        int b = r >> 8;
        int lofs = atomicAdd(&lcur[b], 1);
        unsigned long long packed =
            ((unsigned long long)(unsigned)__float_as_int(vals[idx]) << 32)
            | ((unsigned)(r & 255) << 17) | (unsigned)cols[idx];
        tmp[(size_t)b * CAP + gbase[b] + lofs] = packed;
    }
}

// ---------------------------------------------------------------------------
// 2) per-bucket counting sort by lrow -> rse + padded CSR at b*CAP.
//    Direct scatter to csr: the 32 KB window is L2-resident, so random 8-B
//    stores line-merge in cache (no LDS stage -> 3 KB LDS, high occupancy).
//    Fused: emit needed-rows list for layer 3 (flags -> rowlist/nrows).
// ---------------------------------------------------------------------------
__global__ __launch_bounds__(256) void sort_buckets(
    const unsigned long long* __restrict__ tmp, const int* __restrict__ gcursor,
    const unsigned* __restrict__ flags, int* __restrict__ rowlist,
    int* __restrict__ nrows,
    int2* __restrict__ rse, int2* __restrict__ csr)
{
    __shared__ int lcnt[BROWS], rowcur[BROWS], sdata[BROWS];   // 3 KB
    int b = blockIdx.x;
    int t = threadIdx.x;
    int count = gcursor[b];
    int base  = b * CAP;
    const unsigned long long* src = tmp + (size_t)base;
    lcnt[t] = 0;
    __syncthreads();
    for (int i = t; i < count; i += 256)
        atomicAdd(&lcnt[(int)((src[i] >> 17) & 255)], 1);
    __syncthreads();
    int myc = lcnt[t];
    sdata[t] = myc;
    __syncthreads();
    #pragma unroll
    for (int off = 1; off < 256; off <<= 1) {
        int x = (t >= off) ? sdata[t - off] : 0;
        __syncthreads();
        sdata[t] += x;
        __syncthreads();
    }
    int excl = sdata[t] - myc;
    rowcur[t] = excl;
    int row = b * BROWS + t;
    if (row < NUM_NODES) {
        rse[row] = make_int2(base + excl, base + excl + myc);
        // fused compact_rows
        if ((flags[row >> 5] >> (row & 31)) & 1u) {
            int pos = atomicAdd(nrows, 1);
            rowlist[pos] = row;
        }
    }
    __syncthreads();
    for (int i = t; i < count; i += 256) {
        unsigned long long v = src[i];
        int lr = (int)((v >> 17) & 255);
        int pos = atomicAdd(&rowcur[lr], 1);
        csr[(size_t)base + pos] = make_int2((int)(v & 0x1FFFF), (int)(v >> 32));
    }
}

// ---------------------------------------------------------------------------
// bf16 gather + row accumulate: 8 lanes/row, 16 B (8 bf16) per lane,
// 4x unroll -> 32 independent 128B gathers in flight per wave.
// ---------------------------------------------------------------------------
__device__ __forceinline__ void fma8(
    float acc[8], unsigned long long hx, unsigned long long hy, float v)
{
    unsigned h0 = (unsigned)hx, h1 = (unsigned)(hx >> 32);
    unsigned h2 = (unsigned)hy, h3 = (unsigned)(hy >> 32);
    acc[0] = fmaf(v, __uint_as_float(h0 << 16), acc[0]);
    acc[1] = fmaf(v, __uint_as_float(h0 & 0xFFFF0000u), acc[1]);
    acc[2] = fmaf(v, __uint_as_float(h1 << 16), acc[2]);
    acc[3] = fmaf(v, __uint_as_float(h1 & 0xFFFF0000u), acc[3]);
    acc[4] = fmaf(v, __uint_as_float(h2 << 16), acc[4]);
    acc[5] = fmaf(v, __uint_as_float(h2 & 0xFFFF0000u), acc[5]);
    acc[6] = fmaf(v, __uint_as_float(h3 << 16), acc[6]);
    acc[7] = fmaf(v, __uint_as_float(h3 & 0xFFFF0000u), acc[7]);
}

__device__ __forceinline__ void row_accum8(
    int e, int end, int q, const int2* __restrict__ csr,
    const unsigned short* __restrict__ x16, float acc[8])
{
    typedef unsigned long long u64;
    for (; e + 3 < end; e += 4) {
        int2 p0 = csr[e], p1 = csr[e + 1], p2 = csr[e + 2], p3 = csr[e + 3];
        const u64* s0 = (const u64*)(x16 + ((size_t)p0.x << 6) + (q << 3));
        const u64* s1 = (const u64*)(x16 + ((size_t)p1.x << 6) + (q << 3));
        const u64* s2 = (const u64*)(x16 + ((size_t)p2.x << 6) + (q << 3));
        const u64* s3 = (const u64*)(x16 + ((size_t)p3.x << 6) + (q << 3));
        u64 a0 = s0[0], b0 = s0[1];
        u64 a1 = s1[0], b1 = s1[1];
        u64 a2 = s2[0], b2 = s2[1];
        u64 a3 = s3[0], b3 = s3[1];
        fma8(acc, a0, b0, __int_as_float(p0.y));
        fma8(acc, a1, b1, __int_as_float(p1.y));
        fma8(acc, a2, b2, __int_as_float(p2.y));
        fma8(acc, a3, b3, __int_as_float(p3.y));
    }
    for (; e < end; ++e) {
        int2 p0 = csr[e];
        const u64* s0 = (const u64*)(x16 + ((size_t)p0.x << 6) + (q << 3));
        u64 a0 = s0[0], b0 = s0[1];
        fma8(acc, a0, b0, __int_as_float(p0.y));
    }
}

// dense layer: bf16 in, bf16 out (layers 1 and 2); 8 lanes/row
__global__ __launch_bounds__(256) void spmm_bb(
    const int2* __restrict__ rse, const int2* __restrict__ csr,
    const unsigned short* __restrict__ x16, unsigned short* __restrict__ y16)
{
    int tid = blockIdx.x * blockDim.x + threadIdx.x;
    int row = tid >> 3;
    if (row >= NUM_NODES) return;
    int q = tid & 7;
    int2 se = rse[row];
    float acc[8] = {0.f, 0.f, 0.f, 0.f, 0.f, 0.f, 0.f, 0.f};
    row_accum8(se.x, se.y, q, csr, x16, acc);
    uint4 s;
    s.x = pack2bf(acc[0], acc[1]);
    s.y = pack2bf(acc[2], acc[3]);
    s.z = pack2bf(acc[4], acc[5]);
    s.w = pack2bf(acc[6], acc[7]);
    *(uint4*)(y16 + ((size_t)row << 6) + (q << 3)) = s;
}

// layer 3: listed rows only, bf16 in, fp32 out; 8 lanes/row
__global__ __launch_bounds__(256) void spmm_l3(
    const int* __restrict__ list, const int* __restrict__ nrowsp,
    const int2* __restrict__ rse, const int2* __restrict__ csr,
    const unsigned short* __restrict__ x16, float* __restrict__ y)
{
    int tid = blockIdx.x * blockDim.x + threadIdx.x;
    int i = tid >> 3;
    if (i >= *nrowsp) return;
    int q = tid & 7;
    int row = list[i];
    int2 se = rse[row];
    float acc[8] = {0.f, 0.f, 0.f, 0.f, 0.f, 0.f, 0.f, 0.f};
    row_accum8(se.x, se.y, q, csr, x16, acc);
    float4* yb = (float4*)(y + ((size_t)row << 6) + (q << 3));
    yb[0] = make_float4(acc[0], acc[1], acc[2], acc[3]);
    yb[1] = make_float4(acc[4], acc[5], acc[6], acc[7]);
}

// ---------------------------------------------------------------------------
// batched dot: one wave per batch element
// ---------------------------------------------------------------------------
__global__ __launch_bounds__(256) void dot_kernel(
    const int*   __restrict__ uidx,
    const int*   __restrict__ iidx,
    const float* __restrict__ x,
    float*       __restrict__ out)
{
    int wid  = (blockIdx.x * blockDim.x + threadIdx.x) >> 6;
    int lane = threadIdx.x & 63;
    if (wid >= BATCH) return;
    int u  = uidx[wid];
    int it = iidx[wid];
    float a = x[(size_t)u * DIM + lane];
    float bb = x[((size_t)NUM_USERS + it) * DIM + lane];
    float p = a * bb;
    #pragma unroll
    for (int off = 32; off > 0; off >>= 1)
        p += __shfl_down(p, off);
    if (lane == 0) out[wid] = p;
}

extern "C" void kernel_launch(void* const* d_in, const int* in_sizes, int n_in,
                              void* d_out, int out_size, void* d_ws, size_t ws_size,
                              hipStream_t stream)
{
    const int*   user_indices = (const int*)  d_in[0];
    const int*   item_indices = (const int*)  d_in[1];
    const int*   edge_rows    = (const int*)  d_in[2];
    const int*   edge_cols    = (const int*)  d_in[3];
    const float* edge_vals    = (const float*)d_in[4];
    const float* user_emb     = (const float*)d_in[5];
    const float* item_emb     = (const float*)d_in[6];
    float*       out          = (float*)      d_out;

    // ---- workspace layout ----
    // Alias: bufA (l3 fp32 out, 25.6 MB) overlays tmp (dead after sort_buckets)
    // + xc (dead after layer 1). l3 reads b16A (disjoint region).
    const size_t nfloats = (size_t)NUM_NODES * DIM;   // 6.4M elements
    char* p = (char*)d_ws;
    float* bufA = (float*)p;                            // 25.6 MB span (alias)
    unsigned long long* tmp = (unsigned long long*)p;
    p += (size_t)NBUCK * CAP * 8;                       // 12.81 MB
    unsigned short* xc   = (unsigned short*)p;  p += nfloats * 2;   // 12.8 MB
    unsigned short* b16B = (unsigned short*)p;  p += nfloats * 2;   // 12.8 MB
    unsigned short* b16A = (unsigned short*)p;  p += nfloats * 2;   // 12.8 MB
    int2*     rse     = (int2*)p;     p += 102400 * 8;
    // next three regions contiguous; zeroed by the memset (ZWORDS words)
    int*      gcursor = (int*)p;      p += 512 * 4;
    int*      nrows   = (int*)p;      p += 256 * 4;
    unsigned* flags   = (unsigned*)p; p += 3200 * 4;
    int*      rowlist = (int*)p;      p += 33024 * 4;
    int2*     csr     = (int2*)p;     p += (size_t)NBUCK * CAP * 8; // 12.81 MB

    // ---- zero counters (15.9 KB), fused prep (bin || convert), sort ----
    hipMemsetAsync(gcursor, 0, ZWORDS * sizeof(int), stream);
    prep_kernel<<<NB_BIN + NB_CONV, PREPBLK, 0, stream>>>(
        edge_rows, edge_cols, edge_vals, user_indices, item_indices,
        (const float4*)user_emb, (const float4*)item_emb, (ushort4*)xc,
        gcursor, flags, tmp);
    sort_buckets<<<NBUCK, 256, 0, stream>>>(
        tmp, gcursor, flags, rowlist, nrows, rse, csr);

    // ---- 3 SpMM layers: bf16->bf16, bf16->bf16, bf16->fp32(listed) ----
    const int NB_SPMM = (NUM_NODES * 8 + 255) / 256;   // 3125
    spmm_bb<<<NB_SPMM, 256, 0, stream>>>(rse, csr, xc, b16B);
    spmm_bb<<<NB_SPMM, 256, 0, stream>>>(rse, csr, b16B, b16A);
    spmm_l3<<<(32768 * 8) / 256, 256, 0, stream>>>(
        rowlist, nrows, rse, csr, b16A, bufA);

    // ---- final dot ----
    dot_kernel<<<(BATCH * 64) / 256, 256, 0, stream>>>(
        user_indices, item_indices, bufA, out);
}